// Round 11
// baseline (805.417 us; speedup 1.0000x reference)
//
#include <hip/hip_runtime.h>

// KNN top-16: B=4, N=8192, D=16, k=16, fp32 in, int32 index out.
// Reference model: harness np twin = batched BLAS matmul + numpy SIMD sum:
//   dot  = BLAS microkernel: single-accumulator FMA chain, k = 0..15
//   norm = numpy AVX512 pairwise sum of m_d = fl(x_d^2):
//            r_j = m_j + m_{j+8}           (j=0..7,  512->256 fold)
//            q_j = r_j + r_{j+4}           (j=0..3,  256->128 fold)
//            nrm = fl( fl(q0+q2) + fl(q1+q3) )   (_mm512_reduce_add_ps tail)
//   val  = fl( fl(ni + fl(-2*dot)) + nj )
//   ties -> lower index (no decisive bit-ties observed; moot)
// Scan and refine use the IDENTICAL key; KS=24 margin retained as insurance.

#define B_   4
#define N_   8192
#define D_   16
#define K_   16
#define S_   4              // candidate segments
#define SEG_ (N_ / S_)      // 2048 candidates per segment
#define KS_  24             // per-segment keep: K_ + 8 safety margin
#define CAP_ 16             // per-lane LDS append buffer capacity
#define NQ_  (B_ * N_)      // 32768 queries
#define POOL_ (S_ * KS_)    // 96 pool entries per query

// numpy AVX512 pairwise-sum tree for 16 contiguous floats (see header).
__device__ __forceinline__ float np_norm16(const float* __restrict__ p) {
#pragma clang fp contract(off)
  float m[16];
#pragma unroll
  for (int d = 0; d < 16; ++d) m[d] = p[d] * p[d];
  float r[8];
#pragma unroll
  for (int j = 0; j < 8; ++j) r[j] = m[j] + m[j + 8];
  float q[4];
#pragma unroll
  for (int j = 0; j < 4; ++j) q[j] = r[j] + r[j + 4];
  return (q[0] + q[2]) + (q[1] + q[3]);
}

// BLAS chain-FMA dot (k ascending, single accumulator) + ordered combine.
__device__ __forceinline__ float np_adj(const float* __restrict__ qa,
                                        const float* __restrict__ cj,
                                        float ni, float nj) {
  float dot = 0.f;
#pragma unroll
  for (int d = 0; d < 16; ++d) dot = __builtin_fmaf(qa[d], cj[d], dot);
  float val;
  {
#pragma clang fp contract(off)
    float inner = -2.0f * dot;   // exact power-of-2 scale
    float u = ni + inner;
    val = u + nj;
  }
  return val;
}

__global__ __launch_bounds__(256) void knn_norms(const float* __restrict__ x,
                                                 float* __restrict__ nrm) {
  int q = blockIdx.x * 256 + threadIdx.x;
  float row[16];
  const float4* xv = (const float4*)(x + (size_t)q * D_);
  float4 a = xv[0], b = xv[1], c = xv[2], d = xv[3];
  row[0]=a.x; row[1]=a.y; row[2]=a.z; row[3]=a.w;
  row[4]=b.x; row[5]=b.y; row[6]=b.z; row[7]=b.w;
  row[8]=c.x; row[9]=c.y; row[10]=c.z; row[11]=c.w;
  row[12]=d.x; row[13]=d.y; row[14]=d.z; row[15]=d.w;
  nrm[q] = np_norm16(row);
}

// ascending insert into sorted 24-list; '>' keeps earlier (lower idx) on ties
__device__ __forceinline__ void insert24(float d, int j, float (&kd)[KS_], int (&ki)[KS_]) {
  float cd = d; int ci = j;
#pragma unroll
  for (int p = 0; p < KS_; ++p) {
    bool gt = kd[p] > cd;
    float t0 = gt ? cd : kd[p];
    float t1 = gt ? kd[p] : cd;
    int   t2 = gt ? ci : ki[p];
    int   t3 = gt ? ki[p] : ci;
    kd[p] = t0; cd = t1; ki[p] = t2; ci = t3;
  }
}

__device__ __forceinline__ void flushbuf(unsigned long long (*buf)[256], int tid,
                                         int& count, float& thr,
                                         float (&kd)[KS_], int (&ki)[KS_]) {
#pragma unroll 1
  for (int s = 0; s < CAP_; ++s) {
    if (s < count) {
      unsigned long long e = buf[s][tid];
      float d = __uint_as_float((unsigned)(e >> 32));
      if (d < thr) {
        int j = (int)(e & 0xffffu);
        insert24(d, j, kd, ki);
        thr = kd[KS_ - 1];
      }
    }
  }
  count = 0;
}

__global__ __launch_bounds__(256) void knn_scan(const float* __restrict__ x,
                                                const float* __restrict__ nrm,
                                                unsigned short* __restrict__ pool) {
  __shared__ unsigned long long buf[CAP_][256];   // [slot][tid]: conflict-free
  const int tid = threadIdx.x;
  const int q   = blockIdx.x * 256 + tid;
  const int seg = blockIdx.y;
  const int b   = q >> 13;
  const int row0 = b * N_ + seg * SEG_;
  const float* __restrict__ cbase = x + (size_t)row0 * D_;   // block-uniform
  const float* __restrict__ nbase = nrm + row0;              // block-uniform

  float qa[D_];
  {
    const float4* qv = (const float4*)(x + (size_t)q * D_);
    float4 v0 = qv[0], v1 = qv[1], v2 = qv[2], v3 = qv[3];
    qa[0]=v0.x; qa[1]=v0.y; qa[2]=v0.z; qa[3]=v0.w;
    qa[4]=v1.x; qa[5]=v1.y; qa[6]=v1.z; qa[7]=v1.w;
    qa[8]=v2.x; qa[9]=v2.y; qa[10]=v2.z; qa[11]=v2.w;
    qa[12]=v3.x; qa[13]=v3.y; qa[14]=v3.z; qa[15]=v3.w;
  }
  const float ni = nrm[q];

  float kd[KS_]; int ki[KS_];
#pragma unroll
  for (int p = 0; p < KS_; ++p) { kd[p] = 3.4e38f; ki[p] = 0; }
  float thr = 3.4e38f;
  int count = 0;

  for (int t = 0; t < SEG_; ++t) {
    float c0[D_];
#pragma unroll
    for (int d = 0; d < D_; ++d) c0[d] = cbase[(size_t)t * D_ + d];
    float nj = nbase[t];

    float dist = np_adj(qa, c0, ni, nj);   // IDENTICAL key to refine

    if (dist < thr) {
      buf[count][tid] = ((unsigned long long)__float_as_uint(dist) << 32) | (unsigned)t;
      ++count;
    }
    if (__any(count >= CAP_)) flushbuf(buf, tid, count, thr, kd, ki);
  }
  flushbuf(buf, tid, count, thr, kd, ki);

  unsigned* pp = (unsigned*)(pool + ((size_t)q * S_ + seg) * KS_);
#pragma unroll
  for (int p = 0; p < KS_ / 2; ++p) {
    unsigned lo = (unsigned)(seg * SEG_ + ki[2 * p]);
    unsigned hi = (unsigned)(seg * SEG_ + ki[2 * p + 1]);
    pp[p] = lo | (hi << 16);
  }
}

__global__ __launch_bounds__(256) void knn_refine(const float* __restrict__ x,
                                                  const float* __restrict__ nrm,
                                                  const unsigned short* __restrict__ pool,
                                                  int* __restrict__ out) {
  const int tid  = threadIdx.x;
  const int lane = tid & 63;
  const int q    = blockIdx.x * 4 + (tid >> 6);  // one wave per query
  const int b    = q >> 13;
  const unsigned short* __restrict__ pp = pool + (size_t)q * POOL_;

  float qa[D_];
  {
    const float4* qv = (const float4*)(x + (size_t)q * D_);
    float4 v0 = qv[0], v1 = qv[1], v2 = qv[2], v3 = qv[3];
    qa[0]=v0.x; qa[1]=v0.y; qa[2]=v0.z; qa[3]=v0.w;
    qa[4]=v1.x; qa[5]=v1.y; qa[6]=v1.z; qa[7]=v1.w;
    qa[8]=v2.x; qa[9]=v2.y; qa[10]=v2.z; qa[11]=v2.w;
    qa[12]=v3.x; qa[13]=v3.y; qa[14]=v3.z; qa[15]=v3.w;
  }
  const float ni = nrm[q];

  // 128 slots over 64 lanes: slot0 = lane, slot1 = lane+64 (sentinel if >=96)
  int  j0 = (int)pp[lane];
  bool r1real = (lane + 64) < POOL_;
  int  j1 = r1real ? (int)pp[lane + 64] : (1 << 30);

  float v0, v1;
  {
    float cj[D_];
    const float4* cv = (const float4*)(x + ((size_t)(b * N_) + j0) * D_);
    float4 a = cv[0], bb = cv[1], c = cv[2], d = cv[3];
    cj[0]=a.x; cj[1]=a.y; cj[2]=a.z; cj[3]=a.w;
    cj[4]=bb.x; cj[5]=bb.y; cj[6]=bb.z; cj[7]=bb.w;
    cj[8]=c.x; cj[9]=c.y; cj[10]=c.z; cj[11]=c.w;
    cj[12]=d.x; cj[13]=d.y; cj[14]=d.z; cj[15]=d.w;
    v0 = np_adj(qa, cj, ni, nrm[b * N_ + j0]);
  }
  if (r1real) {
    float cj[D_];
    const float4* cv = (const float4*)(x + ((size_t)(b * N_) + j1) * D_);
    float4 a = cv[0], bb = cv[1], c = cv[2], d = cv[3];
    cj[0]=a.x; cj[1]=a.y; cj[2]=a.z; cj[3]=a.w;
    cj[4]=bb.x; cj[5]=bb.y; cj[6]=bb.z; cj[7]=bb.w;
    cj[8]=c.x; cj[9]=c.y; cj[10]=c.z; cj[11]=c.w;
    cj[12]=d.x; cj[13]=d.y; cj[14]=d.z; cj[15]=d.w;
    v1 = np_adj(qa, cj, ni, nrm[b * N_ + j1]);
  } else {
    v1 = __builtin_inff();
  }

  // exact rank among all 128 slots by (np-key asc, index asc)
  int r0 = 0, r1 = 0;
  for (int t = 0; t < 64; ++t) {
    float a0 = __shfl(v0, t); int b0 = __shfl(j0, t);
    float a1 = __shfl(v1, t); int b1 = __shfl(j1, t);
    r0 += (a0 < v0 || (a0 == v0 && b0 < j0)) ? 1 : 0;
    r0 += (a1 < v0 || (a1 == v0 && b1 < j0)) ? 1 : 0;
    r1 += (a0 < v1 || (a0 == v1 && b0 < j1)) ? 1 : 0;
    r1 += (a1 < v1 || (a1 == v1 && b1 < j1)) ? 1 : 0;
  }
  if (r0 < K_) out[(size_t)q * K_ + r0] = j0;
  if (r1 < K_) out[(size_t)q * K_ + r1] = j1;
}

extern "C" void kernel_launch(void* const* d_in, const int* in_sizes, int n_in,
                              void* d_out, int out_size, void* d_ws, size_t ws_size,
                              hipStream_t stream) {
  const float* x = (const float*)d_in[0];
  float* nrm = (float*)d_ws;                                          // 128 KB
  unsigned short* pool = (unsigned short*)((char*)d_ws + 256 * 1024); // 6 MB
  int* out = (int*)d_out;

  knn_norms<<<NQ_ / 256, 256, 0, stream>>>(x, nrm);
  dim3 g2(NQ_ / 256, S_);
  knn_scan<<<g2, 256, 0, stream>>>(x, nrm, pool);
  knn_refine<<<NQ_ / 4, 256, 0, stream>>>(x, nrm, pool, out);
}

// Round 12
// 715.785 us; speedup vs baseline: 1.1252x; 1.1252x over previous
//
#include <hip/hip_runtime.h>

// KNN top-16: B=4, N=8192, D=16, k=16, fp32 in, int32 index out.
// FROZEN key model (validated R11, absmax=0): harness np twin =
//   dot  = BLAS microkernel single-accumulator FMA chain, k = 0..15
//   norm = numpy AVX512 pairwise tree: r_j=m_j+m_{j+8}; q_j=r_j+r_{j+4};
//          fl(fl(q0+q2)+fl(q1+q3))
//   val  = fl( fl(ni + fl(-2*dot)) + nj ), ties -> lower index
// Scan and refine use the IDENTICAL key -> per-segment top-16 provably
// contains the global top-16 (no margin needed).
// R12 perf: S=8 segments, 64-thread (1-wave) scan blocks -> 4096 waves
// (16 waves/CU, 2x R11 occupancy); unroll-2 candidate loop (2 indep FMA
// chains/lane); CAP=12 LDS push buffer (6 KB/block).

#define B_   4
#define N_   8192
#define D_   16
#define K_   16
#define S_   8              // candidate segments
#define SEG_ (N_ / S_)      // 1024 candidates per segment
#define KS_  16             // per-segment keep (exact key -> no margin)
#define CAP_ 12             // per-lane LDS append buffer capacity
#define BT_  64             // scan block threads (1 wave)
#define NQ_  (B_ * N_)      // 32768 queries
#define POOL_ (S_ * KS_)    // 128 pool entries per query

// numpy AVX512 pairwise-sum tree for 16 contiguous floats. FROZEN.
__device__ __forceinline__ float np_norm16(const float* __restrict__ p) {
#pragma clang fp contract(off)
  float m[16];
#pragma unroll
  for (int d = 0; d < 16; ++d) m[d] = p[d] * p[d];
  float r[8];
#pragma unroll
  for (int j = 0; j < 8; ++j) r[j] = m[j] + m[j + 8];
  float q[4];
#pragma unroll
  for (int j = 0; j < 4; ++j) q[j] = r[j] + r[j + 4];
  return (q[0] + q[2]) + (q[1] + q[3]);
}

// BLAS chain-FMA dot + ordered combine. FROZEN.
__device__ __forceinline__ float np_adj(const float* __restrict__ qa,
                                        const float* __restrict__ cj,
                                        float ni, float nj) {
  float dot = 0.f;
#pragma unroll
  for (int d = 0; d < 16; ++d) dot = __builtin_fmaf(qa[d], cj[d], dot);
  float val;
  {
#pragma clang fp contract(off)
    float inner = -2.0f * dot;   // exact power-of-2 scale
    float u = ni + inner;
    val = u + nj;
  }
  return val;
}

__global__ __launch_bounds__(256) void knn_norms(const float* __restrict__ x,
                                                 float* __restrict__ nrm) {
  int q = blockIdx.x * 256 + threadIdx.x;
  float row[16];
  const float4* xv = (const float4*)(x + (size_t)q * D_);
  float4 a = xv[0], b = xv[1], c = xv[2], d = xv[3];
  row[0]=a.x; row[1]=a.y; row[2]=a.z; row[3]=a.w;
  row[4]=b.x; row[5]=b.y; row[6]=b.z; row[7]=b.w;
  row[8]=c.x; row[9]=c.y; row[10]=c.z; row[11]=c.w;
  row[12]=d.x; row[13]=d.y; row[14]=d.z; row[15]=d.w;
  nrm[q] = np_norm16(row);
}

// ascending insert; '>' keeps earlier (lower idx) on ties
__device__ __forceinline__ void insert16(float d, int j, float (&kd)[KS_], int (&ki)[KS_]) {
  float cd = d; int ci = j;
#pragma unroll
  for (int p = 0; p < KS_; ++p) {
    bool gt = kd[p] > cd;
    float t0 = gt ? cd : kd[p];
    float t1 = gt ? kd[p] : cd;
    int   t2 = gt ? ci : ki[p];
    int   t3 = gt ? ki[p] : ci;
    kd[p] = t0; cd = t1; ki[p] = t2; ci = t3;
  }
}

__device__ __forceinline__ void flushbuf(unsigned long long (*buf)[BT_], int tid,
                                         int& count, float& thr,
                                         float (&kd)[KS_], int (&ki)[KS_]) {
#pragma unroll 1
  for (int s = 0; s < CAP_; ++s) {
    if (s < count) {
      unsigned long long e = buf[s][tid];
      float d = __uint_as_float((unsigned)(e >> 32));
      if (d < thr) {
        int j = (int)(e & 0xffffu);
        insert16(d, j, kd, ki);
        thr = kd[KS_ - 1];
      }
    }
  }
  count = 0;
}

__global__ __launch_bounds__(BT_) void knn_scan(const float* __restrict__ x,
                                                const float* __restrict__ nrm,
                                                unsigned short* __restrict__ pool) {
  __shared__ unsigned long long buf[CAP_][BT_];   // [slot][tid]: conflict-free
  const int tid = threadIdx.x;
  const int q   = blockIdx.x * BT_ + tid;
  const int seg = blockIdx.y;
  const int b   = q >> 13;
  const int row0 = b * N_ + seg * SEG_;
  const float* __restrict__ cbase = x + (size_t)row0 * D_;   // wave-uniform
  const float* __restrict__ nbase = nrm + row0;              // wave-uniform

  float qa[D_];
  {
    const float4* qv = (const float4*)(x + (size_t)q * D_);
    float4 v0 = qv[0], v1 = qv[1], v2 = qv[2], v3 = qv[3];
    qa[0]=v0.x; qa[1]=v0.y; qa[2]=v0.z; qa[3]=v0.w;
    qa[4]=v1.x; qa[5]=v1.y; qa[6]=v1.z; qa[7]=v1.w;
    qa[8]=v2.x; qa[9]=v2.y; qa[10]=v2.z; qa[11]=v2.w;
    qa[12]=v3.x; qa[13]=v3.y; qa[14]=v3.z; qa[15]=v3.w;
  }
  const float ni = nrm[q];

  float kd[KS_]; int ki[KS_];
#pragma unroll
  for (int p = 0; p < KS_; ++p) { kd[p] = 3.4e38f; ki[p] = 0; }
  float thr = 3.4e38f;
  int count = 0;

#pragma unroll 1
  for (int t = 0; t < SEG_; t += 2) {
    // two candidates -> two independent FMA chains (ILP)
    float c0[D_], c1[D_];
#pragma unroll
    for (int d = 0; d < D_; ++d) c0[d] = cbase[(size_t)t * D_ + d];
#pragma unroll
    for (int d = 0; d < D_; ++d) c1[d] = cbase[(size_t)(t + 1) * D_ + d];
    float nj0 = nbase[t];
    float nj1 = nbase[t + 1];

    float d0 = np_adj(qa, c0, ni, nj0);   // IDENTICAL key to refine
    float d1 = np_adj(qa, c1, ni, nj1);

    if (d0 < thr) {
      buf[count][tid] = ((unsigned long long)__float_as_uint(d0) << 32) | (unsigned)t;
      ++count;
    }
    if (d1 < thr) {
      buf[count][tid] = ((unsigned long long)__float_as_uint(d1) << 32) | (unsigned)(t + 1);
      ++count;
    }
    if (__any(count >= CAP_ - 1)) flushbuf(buf, tid, count, thr, kd, ki);
  }
  flushbuf(buf, tid, count, thr, kd, ki);

  unsigned* pp = (unsigned*)(pool + ((size_t)q * S_ + seg) * KS_);
#pragma unroll
  for (int p = 0; p < KS_ / 2; ++p) {
    unsigned lo = (unsigned)(seg * SEG_ + ki[2 * p]);
    unsigned hi = (unsigned)(seg * SEG_ + ki[2 * p + 1]);
    pp[p] = lo | (hi << 16);
  }
}

__global__ __launch_bounds__(256) void knn_refine(const float* __restrict__ x,
                                                  const float* __restrict__ nrm,
                                                  const unsigned short* __restrict__ pool,
                                                  int* __restrict__ out) {
  const int tid  = threadIdx.x;
  const int lane = tid & 63;
  const int q    = blockIdx.x * 4 + (tid >> 6);  // one wave per query
  const int b    = q >> 13;
  const unsigned short* __restrict__ pp = pool + (size_t)q * POOL_;

  float qa[D_];
  {
    const float4* qv = (const float4*)(x + (size_t)q * D_);
    float4 v0 = qv[0], v1 = qv[1], v2 = qv[2], v3 = qv[3];
    qa[0]=v0.x; qa[1]=v0.y; qa[2]=v0.z; qa[3]=v0.w;
    qa[4]=v1.x; qa[5]=v1.y; qa[6]=v1.z; qa[7]=v1.w;
    qa[8]=v2.x; qa[9]=v2.y; qa[10]=v2.z; qa[11]=v2.w;
    qa[12]=v3.x; qa[13]=v3.y; qa[14]=v3.z; qa[15]=v3.w;
  }
  const float ni = nrm[q];

  // 128 slots over 64 lanes: slot0 = lane, slot1 = lane+64 (all real)
  int j0 = (int)pp[lane];
  int j1 = (int)pp[lane + 64];

  float v0, v1;
  {
    float cj[D_];
    const float4* cv = (const float4*)(x + ((size_t)(b * N_) + j0) * D_);
    float4 a = cv[0], bb = cv[1], c = cv[2], d = cv[3];
    cj[0]=a.x; cj[1]=a.y; cj[2]=a.z; cj[3]=a.w;
    cj[4]=bb.x; cj[5]=bb.y; cj[6]=bb.z; cj[7]=bb.w;
    cj[8]=c.x; cj[9]=c.y; cj[10]=c.z; cj[11]=c.w;
    cj[12]=d.x; cj[13]=d.y; cj[14]=d.z; cj[15]=d.w;
    v0 = np_adj(qa, cj, ni, nrm[b * N_ + j0]);
  }
  {
    float cj[D_];
    const float4* cv = (const float4*)(x + ((size_t)(b * N_) + j1) * D_);
    float4 a = cv[0], bb = cv[1], c = cv[2], d = cv[3];
    cj[0]=a.x; cj[1]=a.y; cj[2]=a.z; cj[3]=a.w;
    cj[4]=bb.x; cj[5]=bb.y; cj[6]=bb.z; cj[7]=bb.w;
    cj[8]=c.x; cj[9]=c.y; cj[10]=c.z; cj[11]=c.w;
    cj[12]=d.x; cj[13]=d.y; cj[14]=d.z; cj[15]=d.w;
    v1 = np_adj(qa, cj, ni, nrm[b * N_ + j1]);
  }

  // exact rank among all 128 slots by (np-key asc, index asc)
  int r0 = 0, r1 = 0;
  for (int t = 0; t < 64; ++t) {
    float a0 = __shfl(v0, t); int b0 = __shfl(j0, t);
    float a1 = __shfl(v1, t); int b1 = __shfl(j1, t);
    r0 += (a0 < v0 || (a0 == v0 && b0 < j0)) ? 1 : 0;
    r0 += (a1 < v0 || (a1 == v0 && b1 < j0)) ? 1 : 0;
    r1 += (a0 < v1 || (a0 == v1 && b0 < j1)) ? 1 : 0;
    r1 += (a1 < v1 || (a1 == v1 && b1 < j1)) ? 1 : 0;
  }
  if (r0 < K_) out[(size_t)q * K_ + r0] = j0;
  if (r1 < K_) out[(size_t)q * K_ + r1] = j1;
}

extern "C" void kernel_launch(void* const* d_in, const int* in_sizes, int n_in,
                              void* d_out, int out_size, void* d_ws, size_t ws_size,
                              hipStream_t stream) {
  const float* x = (const float*)d_in[0];
  float* nrm = (float*)d_ws;                                          // 128 KB
  unsigned short* pool = (unsigned short*)((char*)d_ws + 256 * 1024); // 8.4 MB
  int* out = (int*)d_out;

  knn_norms<<<NQ_ / 256, 256, 0, stream>>>(x, nrm);
  dim3 g2(NQ_ / BT_, S_);
  knn_scan<<<g2, BT_, 0, stream>>>(x, nrm, pool);
  knn_refine<<<NQ_ / 4, 256, 0, stream>>>(x, nrm, pool, out);
}

// Round 13
// 605.165 us; speedup vs baseline: 1.3309x; 1.1828x over previous
//
#include <hip/hip_runtime.h>

// KNN top-16: B=4, N=8192, D=16, k=16, fp32 in, int32 index out.
// FROZEN key model (validated R11/R12, absmax=0): harness np twin =
//   dot  = BLAS microkernel single-accumulator FMA chain, k = 0..15
//   norm = numpy AVX512 pairwise tree: r_j=m_j+m_{j+8}; q_j=r_j+r_{j+4};
//          fl(fl(q0+q2)+fl(q1+q3))
//   val  = fl( fl(ni + fl(-2*dot)) + nj ), ties -> lower index
// Scan and refine use the IDENTICAL key -> per-segment top-16 provably
// contains the global top-16.
// R13 perf fix: batch index computed from blockIdx ONLY (wave-uniform) so
// candidate row/norm pointers are SGPR-uniform -> s_load staging instead of
// per-lane VMEM global_load + address math (R12's VALU-overhead limiter).

#define B_   4
#define N_   8192
#define D_   16
#define K_   16
#define S_   8              // candidate segments
#define SEG_ (N_ / S_)      // 1024 candidates per segment
#define KS_  16             // per-segment keep (exact key -> no margin)
#define CAP_ 12             // per-lane LDS append buffer capacity
#define BT_  64             // scan block threads (1 wave)
#define NQ_  (B_ * N_)      // 32768 queries
#define POOL_ (S_ * KS_)    // 128 pool entries per query

// numpy AVX512 pairwise-sum tree for 16 contiguous floats. FROZEN.
__device__ __forceinline__ float np_norm16(const float* __restrict__ p) {
#pragma clang fp contract(off)
  float m[16];
#pragma unroll
  for (int d = 0; d < 16; ++d) m[d] = p[d] * p[d];
  float r[8];
#pragma unroll
  for (int j = 0; j < 8; ++j) r[j] = m[j] + m[j + 8];
  float q[4];
#pragma unroll
  for (int j = 0; j < 4; ++j) q[j] = r[j] + r[j + 4];
  return (q[0] + q[2]) + (q[1] + q[3]);
}

// BLAS chain-FMA dot + ordered combine. FROZEN.
__device__ __forceinline__ float np_adj(const float* __restrict__ qa,
                                        const float* __restrict__ cj,
                                        float ni, float nj) {
  float dot = 0.f;
#pragma unroll
  for (int d = 0; d < 16; ++d) dot = __builtin_fmaf(qa[d], cj[d], dot);
  float val;
  {
#pragma clang fp contract(off)
    float inner = -2.0f * dot;   // exact power-of-2 scale
    float u = ni + inner;
    val = u + nj;
  }
  return val;
}

__global__ __launch_bounds__(256) void knn_norms(const float* __restrict__ x,
                                                 float* __restrict__ nrm) {
  int q = blockIdx.x * 256 + threadIdx.x;
  float row[16];
  const float4* xv = (const float4*)(x + (size_t)q * D_);
  float4 a = xv[0], b = xv[1], c = xv[2], d = xv[3];
  row[0]=a.x; row[1]=a.y; row[2]=a.z; row[3]=a.w;
  row[4]=b.x; row[5]=b.y; row[6]=b.z; row[7]=b.w;
  row[8]=c.x; row[9]=c.y; row[10]=c.z; row[11]=c.w;
  row[12]=d.x; row[13]=d.y; row[14]=d.z; row[15]=d.w;
  nrm[q] = np_norm16(row);
}

// ascending insert; '>' keeps earlier (lower idx) on ties
__device__ __forceinline__ void insert16(float d, int j, float (&kd)[KS_], int (&ki)[KS_]) {
  float cd = d; int ci = j;
#pragma unroll
  for (int p = 0; p < KS_; ++p) {
    bool gt = kd[p] > cd;
    float t0 = gt ? cd : kd[p];
    float t1 = gt ? kd[p] : cd;
    int   t2 = gt ? ci : ki[p];
    int   t3 = gt ? ki[p] : ci;
    kd[p] = t0; cd = t1; ki[p] = t2; ci = t3;
  }
}

__device__ __forceinline__ void flushbuf(unsigned long long (*buf)[BT_], int tid,
                                         int& count, float& thr,
                                         float (&kd)[KS_], int (&ki)[KS_]) {
#pragma unroll 1
  for (int s = 0; s < CAP_; ++s) {
    if (s < count) {
      unsigned long long e = buf[s][tid];
      float d = __uint_as_float((unsigned)(e >> 32));
      if (d < thr) {
        int j = (int)(e & 0xffffu);
        insert16(d, j, kd, ki);
        thr = kd[KS_ - 1];
      }
    }
  }
  count = 0;
}

__global__ __launch_bounds__(BT_) void knn_scan(const float* __restrict__ x,
                                                const float* __restrict__ nrm,
                                                unsigned short* __restrict__ pool) {
  __shared__ unsigned long long buf[CAP_][BT_];   // [slot][tid]: conflict-free
  const int tid = threadIdx.x;
  const int q   = blockIdx.x * BT_ + tid;
  const int seg = blockIdx.y;
  // batch from blockIdx ONLY -> wave-uniform (SGPR) -> s_load staging.
  const int bq  = (int)((blockIdx.x * BT_) >> 13);
  const int row0 = bq * N_ + seg * SEG_;
  const float* __restrict__ cbase = x + (size_t)row0 * D_;   // SGPR pointer
  const float* __restrict__ nbase = nrm + row0;              // SGPR pointer

  float qa[D_];
  {
    const float4* qv = (const float4*)(x + (size_t)q * D_);
    float4 v0 = qv[0], v1 = qv[1], v2 = qv[2], v3 = qv[3];
    qa[0]=v0.x; qa[1]=v0.y; qa[2]=v0.z; qa[3]=v0.w;
    qa[4]=v1.x; qa[5]=v1.y; qa[6]=v1.z; qa[7]=v1.w;
    qa[8]=v2.x; qa[9]=v2.y; qa[10]=v2.z; qa[11]=v2.w;
    qa[12]=v3.x; qa[13]=v3.y; qa[14]=v3.z; qa[15]=v3.w;
  }
  const float ni = nrm[q];

  float kd[KS_]; int ki[KS_];
#pragma unroll
  for (int p = 0; p < KS_; ++p) { kd[p] = 3.4e38f; ki[p] = 0; }
  float thr = 3.4e38f;
  int count = 0;

#pragma unroll 1
  for (int t = 0; t < SEG_; t += 2) {
    // two candidates -> two independent FMA chains; rows stage via s_load
    float c0[D_], c1[D_];
#pragma unroll
    for (int d = 0; d < D_; ++d) c0[d] = cbase[(size_t)t * D_ + d];
#pragma unroll
    for (int d = 0; d < D_; ++d) c1[d] = cbase[(size_t)(t + 1) * D_ + d];
    float nj0 = nbase[t];
    float nj1 = nbase[t + 1];

    float d0 = np_adj(qa, c0, ni, nj0);   // IDENTICAL key to refine
    float d1 = np_adj(qa, c1, ni, nj1);

    if (d0 < thr) {
      buf[count][tid] = ((unsigned long long)__float_as_uint(d0) << 32) | (unsigned)t;
      ++count;
    }
    if (d1 < thr) {
      buf[count][tid] = ((unsigned long long)__float_as_uint(d1) << 32) | (unsigned)(t + 1);
      ++count;
    }
    if (__any(count >= CAP_ - 1)) flushbuf(buf, tid, count, thr, kd, ki);
  }
  flushbuf(buf, tid, count, thr, kd, ki);

  unsigned* pp = (unsigned*)(pool + ((size_t)q * S_ + seg) * KS_);
#pragma unroll
  for (int p = 0; p < KS_ / 2; ++p) {
    unsigned lo = (unsigned)(seg * SEG_ + ki[2 * p]);
    unsigned hi = (unsigned)(seg * SEG_ + ki[2 * p + 1]);
    pp[p] = lo | (hi << 16);
  }
}

__global__ __launch_bounds__(256) void knn_refine(const float* __restrict__ x,
                                                  const float* __restrict__ nrm,
                                                  const unsigned short* __restrict__ pool,
                                                  int* __restrict__ out) {
  const int tid  = threadIdx.x;
  const int lane = tid & 63;
  const int q    = blockIdx.x * 4 + (tid >> 6);  // one wave per query
  const int b    = q >> 13;
  const unsigned short* __restrict__ pp = pool + (size_t)q * POOL_;

  float qa[D_];
  {
    const float4* qv = (const float4*)(x + (size_t)q * D_);
    float4 v0 = qv[0], v1 = qv[1], v2 = qv[2], v3 = qv[3];
    qa[0]=v0.x; qa[1]=v0.y; qa[2]=v0.z; qa[3]=v0.w;
    qa[4]=v1.x; qa[5]=v1.y; qa[6]=v1.z; qa[7]=v1.w;
    qa[8]=v2.x; qa[9]=v2.y; qa[10]=v2.z; qa[11]=v2.w;
    qa[12]=v3.x; qa[13]=v3.y; qa[14]=v3.z; qa[15]=v3.w;
  }
  const float ni = nrm[q];

  // 128 slots over 64 lanes: slot0 = lane, slot1 = lane+64 (all real)
  int j0 = (int)pp[lane];
  int j1 = (int)pp[lane + 64];

  float v0, v1;
  {
    float cj[D_];
    const float4* cv = (const float4*)(x + ((size_t)(b * N_) + j0) * D_);
    float4 a = cv[0], bb = cv[1], c = cv[2], d = cv[3];
    cj[0]=a.x; cj[1]=a.y; cj[2]=a.z; cj[3]=a.w;
    cj[4]=bb.x; cj[5]=bb.y; cj[6]=bb.z; cj[7]=bb.w;
    cj[8]=c.x; cj[9]=c.y; cj[10]=c.z; cj[11]=c.w;
    cj[12]=d.x; cj[13]=d.y; cj[14]=d.z; cj[15]=d.w;
    v0 = np_adj(qa, cj, ni, nrm[b * N_ + j0]);
  }
  {
    float cj[D_];
    const float4* cv = (const float4*)(x + ((size_t)(b * N_) + j1) * D_);
    float4 a = cv[0], bb = cv[1], c = cv[2], d = cv[3];
    cj[0]=a.x; cj[1]=a.y; cj[2]=a.z; cj[3]=a.w;
    cj[4]=bb.x; cj[5]=bb.y; cj[6]=bb.z; cj[7]=bb.w;
    cj[8]=c.x; cj[9]=c.y; cj[10]=c.z; cj[11]=c.w;
    cj[12]=d.x; cj[13]=d.y; cj[14]=d.z; cj[15]=d.w;
    v1 = np_adj(qa, cj, ni, nrm[b * N_ + j1]);
  }

  // exact rank among all 128 slots by (np-key asc, index asc)
  int r0 = 0, r1 = 0;
  for (int t = 0; t < 64; ++t) {
    float a0 = __shfl(v0, t); int b0 = __shfl(j0, t);
    float a1 = __shfl(v1, t); int b1 = __shfl(j1, t);
    r0 += (a0 < v0 || (a0 == v0 && b0 < j0)) ? 1 : 0;
    r0 += (a1 < v0 || (a1 == v0 && b1 < j0)) ? 1 : 0;
    r1 += (a0 < v1 || (a0 == v1 && b0 < j1)) ? 1 : 0;
    r1 += (a1 < v1 || (a1 == v1 && b1 < j1)) ? 1 : 0;
  }
  if (r0 < K_) out[(size_t)q * K_ + r0] = j0;
  if (r1 < K_) out[(size_t)q * K_ + r1] = j1;
}

extern "C" void kernel_launch(void* const* d_in, const int* in_sizes, int n_in,
                              void* d_out, int out_size, void* d_ws, size_t ws_size,
                              hipStream_t stream) {
  const float* x = (const float*)d_in[0];
  float* nrm = (float*)d_ws;                                          // 128 KB
  unsigned short* pool = (unsigned short*)((char*)d_ws + 256 * 1024); // 8.4 MB
  int* out = (int*)d_out;

  knn_norms<<<NQ_ / 256, 256, 0, stream>>>(x, nrm);
  dim3 g2(NQ_ / BT_, S_);
  knn_scan<<<g2, BT_, 0, stream>>>(x, nrm, pool);
  knn_refine<<<NQ_ / 4, 256, 0, stream>>>(x, nrm, pool, out);
}